// Round 1
// baseline (86.363 us; speedup 1.0000x reference)
//
#include <hip/hip_runtime.h>
#include <math.h>

typedef _Float16 f16;
typedef __attribute__((ext_vector_type(4))) _Float16 f16x4;
typedef __attribute__((ext_vector_type(8))) _Float16 f16x8;
typedef __attribute__((ext_vector_type(16))) float f32x16;

// sat (128,4,64,16) f32, grd (128,4,64,16) f32
// out (f32): sat 524288 | grd 524288 | distance[g][s] 16384 | orien[s][g] 16384
#define DIST_OFF  1048576
#define ORI_OFF   1064960
#define SATP_STR  72      // f16 elems per satP row (144 B = 36 dwords -> quad = row mod 8, conflict-free)

#define MFMA(a,b,c) __builtin_amdgcn_mfma_f32_32x32x16_f16((a),(b),(c),0,0,0)

// ---- prep: grd -> frag-ready grdF[kb][g][e] hi/lo (k = dw*64 + h*16 + c), LDS-tiled ----
// 64 blocks: transpose/convert only (copies moved to corr_k tail).
__global__ __launch_bounds__(256) void prep_k(const float* __restrict__ grd,
                                              f16* __restrict__ gHi, f16* __restrict__ gLo) {
    const int b = blockIdx.x;
    __shared__ f16 tH[8192], tL[8192];          // [kb_l 64][g_l 16][e 8]
    const int tid = threadIdx.x;
    const int g0 = (b & 7) * 16;
    const int kq = b >> 3;                      // k-range [kq*512, kq*512+512)
    #pragma unroll
    for (int i = 0; i < 32; ++i) {
        int flat = i * 256 + tid;               // [g_l 16][h 4][j 128], coalesced reads
        int g_l = flat >> 9;
        int r   = flat & 511;
        int h   = r >> 7;
        int j   = r & 127;                      // dw_l = j>>4, c = j&15
        float v = grd[(((g0 + g_l) * 4 + h) * 64 + kq * 8) * 16 + j];
        int k_l = (j >> 4) * 64 + h * 16 + (j & 15);
        f16 hv = (f16)v;
        int a = (k_l >> 3) * 128 + g_l * 8 + (k_l & 7);
        tH[a] = hv;
        tL[a] = (f16)(v - (float)hv);
    }
    __syncthreads();
    #pragma unroll
    for (int i = 0; i < 4; ++i) {
        int f = i * 256 + tid;                  // frag: kb_l = f>>4, g_l = f&15
        int dst = (kq * 64 + (f >> 4)) * 128 + g0 + (f & 15);
        ((f16x8*)gHi)[dst] = *(const f16x8*)(tH + f * 8);
        ((f16x8*)gLo)[dst] = *(const f16x8*)(tL + f * 8);
    }
}

// ---- corr: block=(s, g-half64), 8 waves = 8-way K split, wave tile 64j x 64g ----
__global__ __launch_bounds__(512, 2) void corr_k(const float* __restrict__ sat,
                                                 const f16* __restrict__ gHi,
                                                 const f16* __restrict__ gLo,
                                                 float* __restrict__ out,
                                                 const float4* __restrict__ satIn,
                                                 const float4* __restrict__ grdIn,
                                                 float4* __restrict__ out4,
                                                 int doCopy) {
    __shared__ __align__(16) unsigned char smem[131072];  // satP (36.6KB) then red (128KB)
    __shared__ float wred[8];
    __shared__ float rnormS;
    f16* sH = (f16*)smem;                 // [w' 0..126][hc 0..63], stride 72
    f16* sL = sH + 127 * SATP_STR;
    float* red = (float*)smem;            // [kh 8][j 64][g 64]

    const int tid = threadIdx.x;
    const int s  = blockIdx.x >> 1;
    const int gh = blockIdx.x & 1;
    const int wave = tid >> 6, lane = tid & 63;
    const int m = lane & 31, half = lane >> 5;

    // ---- stage satP hi/lo (doubled along w), float4 loads + f16x4 LDS writes; ||sat[s]||^2 ----
    const float4* satS4 = (const float4*)(sat + s * 4096);
    float ssq = 0.f;
    #pragma unroll
    for (int r = 0; r < 2; ++r) {
        int i4 = r * 512 + tid;                  // 0..1023 float4 (4096 floats)
        float4 v = satS4[i4];
        int h = i4 >> 8, w = (i4 >> 2) & 63;
        int col = h * 16 + (i4 & 3) * 4;
        f16x4 hq = {(f16)v.x, (f16)v.y, (f16)v.z, (f16)v.w};
        f16x4 lq = {(f16)(v.x - (float)hq[0]), (f16)(v.y - (float)hq[1]),
                    (f16)(v.z - (float)hq[2]), (f16)(v.w - (float)hq[3])};
        *(f16x4*)(sH + w * SATP_STR + col) = hq;
        *(f16x4*)(sL + w * SATP_STR + col) = lq;
        if (w < 63) {
            *(f16x4*)(sH + (w + 64) * SATP_STR + col) = hq;
            *(f16x4*)(sL + (w + 64) * SATP_STR + col) = lq;
        }
        ssq += v.x * v.x + v.y * v.y + v.z * v.z + v.w * v.w;
    }
    #pragma unroll
    for (int off = 32; off > 0; off >>= 1) ssq += __shfl_down(ssq, off, 64);
    if (lane == 0) wred[wave] = ssq;
    __syncthreads();
    if (tid == 0) {
        float t = 0.f;
        #pragma unroll
        for (int i = 0; i < 8; ++i) t += wred[i];
        rnormS = 1.f / fmaxf(sqrtf(t), 1e-12f);
    }

    // ---- K-loop: kh = wave, 32 k-tiles of 16; 2-deep LDS A, 3-deep global B prefetch ----
    const f16* A0h = sH + m * SATP_STR + half * 8;
    const f16* A0l = sL + m * SATP_STR + half * 8;
    const f16x8* BHp = (const f16x8*)gHi;
    const f16x8* BLp = (const f16x8*)gLo;
    const int ggBase = half * 128 + gh * 64 + m;

    f32x16 z;
    #pragma unroll
    for (int r = 0; r < 16; ++r) z[r] = 0.f;
    f32x16 h00 = z, h01 = z, h10 = z, h11 = z, x00 = z, x01 = z, x10 = z, x11 = z;

    f16x8 ah[2][2], al[2][2], bh[3][2], bl[3][2];

#define LOADA(p, t) { \
    int ao = ((t) >> 2) * SATP_STR + ((t) & 3) * 16; \
    ah[p][0] = *(const f16x8*)(A0h + ao); \
    ah[p][1] = *(const f16x8*)(A0h + ao + 32 * SATP_STR); \
    al[p][0] = *(const f16x8*)(A0l + ao); \
    al[p][1] = *(const f16x8*)(A0l + ao + 32 * SATP_STR); }

#define LOADB(p, t) { \
    int bu = (t) * 256 + ggBase; \
    bh[p][0] = BHp[bu]; bh[p][1] = BHp[bu + 32]; \
    bl[p][0] = BLp[bu]; bl[p][1] = BLp[bu + 32]; }

#define STEP(p, q) { \
    __builtin_amdgcn_s_setprio(1); \
    h00 = MFMA(ah[p][0], bh[q][0], h00); \
    h01 = MFMA(ah[p][0], bh[q][1], h01); \
    h10 = MFMA(ah[p][1], bh[q][0], h10); \
    h11 = MFMA(ah[p][1], bh[q][1], h11); \
    x00 = MFMA(ah[p][0], bl[q][0], x00); x00 = MFMA(al[p][0], bh[q][0], x00); \
    x01 = MFMA(ah[p][0], bl[q][1], x01); x01 = MFMA(al[p][0], bh[q][1], x01); \
    x10 = MFMA(ah[p][1], bl[q][0], x10); x10 = MFMA(al[p][1], bh[q][0], x10); \
    x11 = MFMA(ah[p][1], bl[q][1], x11); x11 = MFMA(al[p][1], bh[q][1], x11); \
    __builtin_amdgcn_s_setprio(0); }

    const int t0 = wave * 32;
    LOADB(0, t0) LOADB(1, t0 + 1) LOADB(2, t0 + 2)
    LOADA(0, t0)
    #pragma unroll
    for (int tt = 0; tt < 32; ++tt) {
        if (tt < 31) LOADA((tt + 1) & 1, t0 + tt + 1)
        STEP(tt & 1, tt % 3)
        if (tt < 29) LOADB(tt % 3, t0 + tt + 3)
    }
    h00 = h00 + x00; h01 = h01 + x01; h10 = h10 + x10; h11 = h11 + x11;

    // ---- flat 8-partial reduce (satP dead; red reuses smem) ----
    __syncthreads();
    float* rw = red + wave * 4096;
    #pragma unroll
    for (int r = 0; r < 16; ++r) {
        int j0 = (r & 3) + 8 * (r >> 2) + 4 * half;      // j within 32-tile
        rw[j0 * 64 + m]             = h00[r];
        rw[j0 * 64 + 32 + m]        = h01[r];
        rw[(j0 + 32) * 64 + m]      = h10[r];
        rw[(j0 + 32) * 64 + 32 + m] = h11[r];
    }
    __syncthreads();
    #pragma unroll
    for (int i = 0; i < 8; ++i) {
        int c = i * 512 + tid;                           // j = c>>6, g = c&63
        float v = red[c]         + red[c + 4096]  + red[c + 8192]  + red[c + 12288]
                + red[c + 16384] + red[c + 20480] + red[c + 24576] + red[c + 28672];
        red[c] = v;                                      // own-cell only: race-free
    }
    __syncthreads();

    // ---- argmax over j (first occurrence), distance + orien ----
    if (tid < 64) {
        int g = tid;
        float best = red[g];
        int bj = 0;
        for (int j = 1; j < 64; ++j) {
            float v = red[j * 64 + g];
            if (v > best) { best = v; bj = j; }
        }
        float dot = best * rnormS;
        int gg = gh * 64 + g;
        out[DIST_OFF + gg * 128 + s] = 2.f - 2.f * dot;
        out[ORI_OFF + s * 128 + gg]  = (float)bj;
    }

    // ---- fused passthrough copies (useWs path): hidden in wave drain ----
    if (doCopy) {
        int i = blockIdx.x * 512 + tid;                  // 256 blocks x 512 = 131072 float4
        out4[i] = satIn[i];
        out4[131072 + i] = grdIn[i];
    }
}

// Fallback passthrough copies (when grdF was staged inside d_out's sat region)
__global__ void copy_k(const float4* __restrict__ a, const float4* __restrict__ b,
                       float4* __restrict__ out) {
    int i = blockIdx.x * 256 + threadIdx.x;
    out[i] = a[i];
    out[131072 + i] = b[i];
}

extern "C" void kernel_launch(void* const* d_in, const int* in_sizes, int n_in,
                              void* d_out, int out_size, void* d_ws, size_t ws_size,
                              hipStream_t stream) {
    const float* sat = (const float*)d_in[0];
    const float* grd = (const float*)d_in[1];
    float* out = (float*)d_out;

    const bool useWs = (ws_size >= (size_t)2 * 1024 * 1024);
    f16* gHi;
    f16* gLo;
    if (useWs) {
        gHi = (f16*)d_ws;
        gLo = gHi + 524288;
    } else {
        gHi = (f16*)out;                 // floats [0, 262144)
        gLo = (f16*)(out + 262144);      // floats [262144, 524288)
    }

    prep_k<<<64, 256, 0, stream>>>(grd, gHi, gLo);
    corr_k<<<256, 512, 0, stream>>>(sat, gHi, gLo, out,
                                    (const float4*)sat, (const float4*)grd, (float4*)out,
                                    useWs ? 1 : 0);
    if (!useWs)
        copy_k<<<512, 256, 0, stream>>>((const float4*)sat, (const float4*)grd, (float4*)out);
}